// Round 1
// baseline (767.851 us; speedup 1.0000x reference)
//
#include <hip/hip_runtime.h>

#define BATCH   4096
#define LEAVES  64
#define LDIM    50
#define ARG     5
#define K1      300    // (1+ARG)*L
#define K2      150    // 3*L
#define OUTD    155    // 3*L+5
#define NTHREADS 256

__global__ __launch_bounds__(NTHREADS) void formula_net_kernel(
    const int*   __restrict__ pred_ids,   // B*64
    const int*   __restrict__ arg_ids,    // B*64*5
    const int*   __restrict__ op_ids,     // B*63
    const float* __restrict__ emb_pred,   // 100*50
    const float* __restrict__ emb_var,    // 100*50
    const float* __restrict__ emb_op,     // 100*50
    const float* __restrict__ W_pred,     // 50 x 300
    const float* __restrict__ b_pred,     // 50
    const float* __restrict__ W_bin,      // 50 x 150
    const float* __restrict__ b_bin,      // 50
    const float* __restrict__ W_final,    // 155 x 50
    const float* __restrict__ b_final,    // 155
    float*       __restrict__ out)        // B x 155
{
    const int b   = blockIdx.x;
    const int tid = threadIdx.x;

    __shared__ int   s_pred[LEAVES];
    __shared__ int   s_arg[LEAVES * ARG];
    __shared__ int   s_op[LEAVES - 1];
    __shared__ float s_cat[16][K1];          // 16 leaves x 300
    __shared__ float s_xA[LEAVES][LDIM];     // ping (64 rows)
    __shared__ float s_xB[LEAVES / 2][LDIM]; // pong (32 rows)
    __shared__ float s_opv[32][LDIM];

    // ---- stage indices ----
    if (tid < LEAVES)     s_pred[tid] = pred_ids[b * LEAVES + tid];
    for (int i = tid; i < LEAVES * ARG; i += NTHREADS)
        s_arg[i] = arg_ids[b * LEAVES * ARG + i];
    if (tid < LEAVES - 1) s_op[tid] = op_ids[b * (LEAVES - 1) + tid];
    __syncthreads();

    // ---- leaf layer: 4 chunks of 16 leaves ----
    for (int c = 0; c < 4; ++c) {
        const int leaf0 = c * 16;
        // gather cat = [emb_pred[pid] | emb_var[a0..a4]] into LDS
        for (int i = tid; i < 16 * K1; i += NTHREADS) {
            int lf = i / K1;
            int k  = i - lf * K1;
            int gleaf = leaf0 + lf;
            float v;
            if (k < LDIM) {
                v = emb_pred[s_pred[gleaf] * LDIM + k];
            } else {
                int a  = (k - LDIM) / LDIM;          // 0..4
                int kk = (k - LDIM) - a * LDIM;      // 0..49
                v = emb_var[s_arg[gleaf * ARG + a] * LDIM + kk];
            }
            s_cat[lf][k] = v;
        }
        __syncthreads();
        // compute 16 leaves x 50 outputs
        for (int idx = tid; idx < 16 * LDIM; idx += NTHREADS) {
            int lf = idx & 15;
            int j  = idx >> 4;
            const float4* cp = reinterpret_cast<const float4*>(&s_cat[lf][0]);
            const float4* wp = reinterpret_cast<const float4*>(&W_pred[j * K1]);
            float ax = 0.f, ay = 0.f, az = 0.f, aw = 0.f;
            #pragma unroll 5
            for (int q = 0; q < K1 / 4; ++q) {
                float4 cv = cp[q];
                float4 wv = wp[q];
                ax += cv.x * wv.x; ay += cv.y * wv.y;
                az += cv.z * wv.z; aw += cv.w * wv.w;
            }
            float r = ax + ay + az + aw + b_pred[j];
            s_xA[leaf0 + lf][j] = fmaxf(r, 0.f);
        }
        __syncthreads();  // protect s_cat before next chunk's gather
    }

    // ---- tree levels ----
    const int offs[6] = {0, 32, 48, 56, 60, 62};
    for (int lev = 0; lev < 6; ++lev) {
        const int sh  = 5 - lev;
        const int n   = 1 << sh;          // 32,16,8,4,2,1
        const int off = offs[lev];
        // gather op embeddings for this level
        for (int i = tid; i < n * LDIM; i += NTHREADS) {
            int node = i / LDIM;
            int k    = i - node * LDIM;
            s_opv[node][k] = emb_op[s_op[off + node] * LDIM + k];
        }
        __syncthreads();
        const bool srcA = (lev & 1) == 0;  // lev0 reads xA
        for (int idx = tid; idx < n * LDIM; idx += NTHREADS) {
            int node = idx & (n - 1);
            int j    = idx >> sh;
            const float* lrow = srcA ? s_xA[2 * node]     : s_xB[2 * node];
            const float* rrow = srcA ? s_xA[2 * node + 1] : s_xB[2 * node + 1];
            const float* orow = s_opv[node];
            const float* wl   = &W_bin[j * K2];
            float a0x=0.f,a0y=0.f,a1x=0.f,a1y=0.f,a2x=0.f,a2y=0.f;
            #pragma unroll
            for (int q = 0; q < LDIM / 2; ++q) {
                float2 lv = reinterpret_cast<const float2*>(lrow)[q];
                float2 ov = reinterpret_cast<const float2*>(orow)[q];
                float2 rv = reinterpret_cast<const float2*>(rrow)[q];
                float2 w0 = reinterpret_cast<const float2*>(wl)[q];
                float2 w1 = reinterpret_cast<const float2*>(wl + LDIM)[q];
                float2 w2 = reinterpret_cast<const float2*>(wl + 2 * LDIM)[q];
                a0x += lv.x * w0.x; a0y += lv.y * w0.y;
                a1x += ov.x * w1.x; a1y += ov.y * w1.y;
                a2x += rv.x * w2.x; a2y += rv.y * w2.y;
            }
            float r = a0x + a0y + a1x + a1y + a2x + a2y + b_bin[j];
            r = fmaxf(r, 0.f);
            if (srcA) s_xB[node][j] = r;
            else      s_xA[node][j] = r;
        }
        __syncthreads();
    }
    // after 6 levels (last level read xB, wrote xA): root = s_xA[0]

    // ---- final head: 155 outputs ----
    for (int o = tid; o < OUTD; o += NTHREADS) {
        const float* w = &W_final[o * LDIM];
        float acc = b_final[o];
        #pragma unroll
        for (int k = 0; k < LDIM; ++k)
            acc += s_xA[0][k] * w[k];
        out[b * OUTD + o] = acc;
    }
}

extern "C" void kernel_launch(void* const* d_in, const int* in_sizes, int n_in,
                              void* d_out, int out_size, void* d_ws, size_t ws_size,
                              hipStream_t stream) {
    const int*   pred_ids = (const int*)  d_in[0];
    const int*   arg_ids  = (const int*)  d_in[1];
    const int*   op_ids   = (const int*)  d_in[2];
    const float* emb_pred = (const float*)d_in[3];
    const float* emb_var  = (const float*)d_in[4];
    const float* emb_op   = (const float*)d_in[5];
    const float* W_pred   = (const float*)d_in[6];
    const float* b_pred   = (const float*)d_in[7];
    const float* W_bin    = (const float*)d_in[8];
    const float* b_bin    = (const float*)d_in[9];
    const float* W_final  = (const float*)d_in[10];
    const float* b_final  = (const float*)d_in[11];
    float* out = (float*)d_out;

    hipLaunchKernelGGL(formula_net_kernel, dim3(BATCH), dim3(NTHREADS), 0, stream,
                       pred_ids, arg_ids, op_ids, emb_pred, emb_var, emb_op,
                       W_pred, b_pred, W_bin, b_bin, W_final, b_final, out);
}

// Round 2
// 121.739 us; speedup vs baseline: 6.3073x; 6.3073x over previous
//
#include <hip/hip_runtime.h>

using short8 = __attribute__((ext_vector_type(8))) short;
using f32x4  = __attribute__((ext_vector_type(4))) float;

#define NB   16      // batch elements per block
#define NTH  512     // 8 waves
// d_ws layout (ushort units)
#define WPRED_OFF 0        // [64 n][384 k]  (6 pieces x 64, 50 data each)
#define WBIN_OFF  24576    // [64 n][192 k]  (3 pieces x 64)
#define EMBP_OFF  36864    // [100][64]
#define EMBV_OFF  43264    // [100][64]
#define EMBO_OFF  49664    // [100][64]
#define WS_USHORTS 56064

// float -> bf16 (RNE), bit-level, no NaN inputs expected
__device__ __forceinline__ unsigned short f2b(float v) {
    unsigned x = __float_as_uint(v);
    unsigned r = (x + 0x7fffu + ((x >> 16) & 1u)) >> 16;
    return (unsigned short)r;
}

__device__ __forceinline__ short8 ld8s(const unsigned short* p) {
    return *reinterpret_cast<const short8*>(p);
}

__device__ __forceinline__ f32x4 mf(short8 a, short8 b, f32x4 c) {
    return __builtin_amdgcn_mfma_f32_16x16x32_bf16(a, b, c, 0, 0, 0);
}

// ---------------- prep: convert weights + embeddings to padded bf16 in ws ----
__global__ void prep_kernel(const float* __restrict__ emb_pred,
                            const float* __restrict__ emb_var,
                            const float* __restrict__ emb_op,
                            const float* __restrict__ W_pred,
                            const float* __restrict__ W_bin,
                            unsigned short* __restrict__ ws) {
    for (int i = blockIdx.x * blockDim.x + threadIdx.x; i < WS_USHORTS;
         i += gridDim.x * blockDim.x) {
        float v = 0.f;
        if (i < WBIN_OFF) {                     // W_pred_b [64][384]
            int n = i / 384, k = i - n * 384, p = k >> 6, j = k & 63;
            if (n < 50 && j < 50) v = W_pred[n * 300 + p * 50 + j];
        } else if (i < EMBP_OFF) {              // W_bin_b [64][192]
            int t = i - WBIN_OFF;
            int n = t / 192, k = t - n * 192, p = k >> 6, j = k & 63;
            if (n < 50 && j < 50) v = W_bin[n * 150 + p * 50 + j];
        } else {                                // emb tables [100][64]
            int t = i - EMBP_OFF;
            int tab = t / 6400, rj = t - tab * 6400, r = rj >> 6, j = rj & 63;
            const float* e = (tab == 0) ? emb_pred : (tab == 1 ? emb_var : emb_op);
            if (j < 50) v = e[r * 50 + j];
        }
        ws[i] = f2b(v);
    }
}

// ---------------- main fused kernel -----------------------------------------
// Block = 16 batch elements. 8 waves = 2 subtree-groups x 4 N-tile waves.
// Activation rows in LDS: [16 batch][64 bf16], XOR-swizzled in 8-elem slots:
//   phys elem = b*64 + ((k>>3 ^ (b&7))<<3) + (k&7)
// s_x row map: 0..31 leafbuf(g*16+lf) | 32..47 L0(32+g*8+j) | 48..55 L1
//              56..59 L2 | 60..63 L3(st) | 64..65 L4(g) | 66 root
__global__ __launch_bounds__(NTH, 2) void formula_kernel(
    const int* __restrict__ pred_ids, const int* __restrict__ arg_ids,
    const int* __restrict__ op_ids,
    const float* __restrict__ b_pred, const float* __restrict__ b_bin,
    const float* __restrict__ W_final, const float* __restrict__ b_final,
    const unsigned short* __restrict__ ws,
    float* __restrict__ out)
{
    __shared__ __align__(16) unsigned short s_x[67][1024];
    __shared__ unsigned char s_pred[64 * 16];
    __shared__ unsigned char s_arg[320 * 16];
    __shared__ unsigned char s_op[63 * 16 + 16];

    const int tid  = threadIdx.x;
    const int b0   = blockIdx.x * NB;
    const int lane = tid & 63;
    const int w    = tid >> 6;       // wave 0..7
    const int g    = w >> 2;         // subtree group 0..1
    const int nt   = w & 3;          // N-tile 0..3
    const int l15  = lane & 15;      // batch row (A) / out col (D)
    const int quad = lane >> 4;      // k-quad
    const int n    = nt * 16 + l15;  // output neuron this lane owns

    // ---- stage indices as u8, transposed to [entry][batch] ----
    for (int e = tid; e < 64 * 16; e += NTH) {
        int batch = e >> 6, lf = e & 63;
        s_pred[lf * 16 + batch] = (unsigned char)pred_ids[(b0 + batch) * 64 + lf];
    }
    for (int e = tid; e < 320 * 16; e += NTH) {
        int batch = e / 320, r = e - batch * 320;
        s_arg[r * 16 + batch] = (unsigned char)arg_ids[(b0 + batch) * 320 + r];
    }
    for (int e = tid; e < 63 * 16; e += NTH) {
        int batch = e / 63, r = e - batch * 63;
        s_op[r * 16 + batch] = (unsigned char)op_ids[(b0 + batch) * 63 + r];
    }

    // ---- persistent B fragments (weights) in registers ----
    short8 wp[6][2], wb[3][2];
    {
        const unsigned short* base = ws + WPRED_OFF + n * 384 + quad * 8;
        #pragma unroll
        for (int p = 0; p < 6; ++p) {
            wp[p][0] = ld8s(base + p * 64);
            wp[p][1] = ld8s(base + p * 64 + 32);
        }
        const unsigned short* bb = ws + WBIN_OFF + n * 192 + quad * 8;
        #pragma unroll
        for (int p = 0; p < 3; ++p) {
            wb[p][0] = ld8s(bb + p * 64);
            wb[p][1] = ld8s(bb + p * 64 + 32);
        }
    }
    const float bias_p = (n < 50) ? b_pred[n] : 0.f;
    const float bias_b = (n < 50) ? b_bin[n]  : 0.f;

    const int sl0 = (quad ^ (l15 & 7)) * 8;          // phys slot bytes/2, kstep 0
    const int sl1 = ((4 + quad) ^ (l15 & 7)) * 8;    // kstep 1

    // D: col=lane&15 (=n), row=(lane>>4)*4+q (=batch m). ReLU+bias, swizzled store.
    auto epi = [&](f32x4 acc, float bias, unsigned short* row) {
        #pragma unroll
        for (int q = 0; q < 4; ++q) {
            int m = quad * 4 + q;
            float v = fmaxf(acc[q] + bias, 0.f);
            row[m * 64 + (((n >> 3) ^ (m & 7)) << 3) + (n & 7)] = f2b(v);
        }
    };

    // one binary-tree node: acc over [left | op | right] pieces
    auto tnode = [&](int cl, int cr, int gn, int dst) {
        f32x4 acc = {0.f, 0.f, 0.f, 0.f};
        const unsigned short* rl = s_x[cl];
        const unsigned short* rr = s_x[cr];
        acc = mf(ld8s(rl + l15 * 64 + sl0), wb[0][0], acc);
        acc = mf(ld8s(rl + l15 * 64 + sl1), wb[0][1], acc);
        int id = s_op[gn * 16 + l15];
        const unsigned short* eo = ws + EMBO_OFF + id * 64 + quad * 8;
        acc = mf(ld8s(eo),      wb[1][0], acc);
        acc = mf(ld8s(eo + 32), wb[1][1], acc);
        acc = mf(ld8s(rr + l15 * 64 + sl0), wb[2][0], acc);
        acc = mf(ld8s(rr + l15 * 64 + sl1), wb[2][1], acc);
        epi(acc, bias_b, s_x[dst]);
    };

    __syncthreads();

    for (int sp = 0; sp < 2; ++sp) {
        const int st = 2 * g + sp;           // subtree 0..3 (16 leaves each)
        // ---- leaf layer ----
        for (int lf = 0; lf < 16; ++lf) {
            const int gl = st * 16 + lf;
            f32x4 acc = {0.f, 0.f, 0.f, 0.f};
            {
                int id = s_pred[gl * 16 + l15];
                const unsigned short* ep = ws + EMBP_OFF + id * 64 + quad * 8;
                acc = mf(ld8s(ep),      wp[0][0], acc);
                acc = mf(ld8s(ep + 32), wp[0][1], acc);
            }
            #pragma unroll
            for (int a = 0; a < 5; ++a) {
                int id = s_arg[(gl * 5 + a) * 16 + l15];
                const unsigned short* ev = ws + EMBV_OFF + id * 64 + quad * 8;
                acc = mf(ld8s(ev),      wp[1 + a][0], acc);
                acc = mf(ld8s(ev + 32), wp[1 + a][1], acc);
            }
            epi(acc, bias_p, s_x[g * 16 + lf]);
        }
        __syncthreads();
        // ---- lev0: 8 nodes ----
        for (int j = 0; j < 8; ++j)
            tnode(g * 16 + 2 * j, g * 16 + 2 * j + 1, 0 + st * 8 + j, 32 + g * 8 + j);
        __syncthreads();
        // ---- lev1: 4 nodes ----
        for (int j = 0; j < 4; ++j)
            tnode(32 + g * 8 + 2 * j, 32 + g * 8 + 2 * j + 1, 32 + st * 4 + j, 48 + g * 4 + j);
        __syncthreads();
        // ---- lev2: 2 nodes ----
        for (int j = 0; j < 2; ++j)
            tnode(48 + g * 4 + 2 * j, 48 + g * 4 + 2 * j + 1, 48 + st * 2 + j, 56 + g * 2 + j);
        __syncthreads();
        // ---- lev3: 1 node -> shared L3[st] ----
        tnode(56 + g * 2, 56 + g * 2 + 1, 56 + st, 60 + st);
        __syncthreads();
    }
    // ---- lev4: group g computes node g ----
    tnode(60 + 2 * g, 60 + 2 * g + 1, 60 + g, 64 + g);
    __syncthreads();
    // ---- lev5 (root): group 0 only ----
    if (g == 0) tnode(64, 65, 62, 66);
    __syncthreads();

    // ---- final head: fp32, 16 batches x 155 outputs ----
    const int hb = tid >> 5;   // batch 0..15
    const int ln = tid & 31;
    float xr[50];
    #pragma unroll
    for (int k = 0; k < 50; ++k) {
        unsigned short u = s_x[66][hb * 64 + (((k >> 3) ^ (hb & 7)) << 3) + (k & 7)];
        xr[k] = __uint_as_float(((unsigned)u) << 16);
    }
    for (int o = ln; o < 155; o += 32) {
        float acc = b_final[o];
        const float* wf = W_final + o * 50;
        #pragma unroll
        for (int k = 0; k < 50; ++k) acc += xr[k] * wf[k];
        out[(b0 + hb) * 155 + o] = acc;
    }
}

extern "C" void kernel_launch(void* const* d_in, const int* in_sizes, int n_in,
                              void* d_out, int out_size, void* d_ws, size_t ws_size,
                              hipStream_t stream) {
    const int*   pred_ids = (const int*)  d_in[0];
    const int*   arg_ids  = (const int*)  d_in[1];
    const int*   op_ids   = (const int*)  d_in[2];
    const float* emb_pred = (const float*)d_in[3];
    const float* emb_var  = (const float*)d_in[4];
    const float* emb_op   = (const float*)d_in[5];
    const float* W_pred   = (const float*)d_in[6];
    const float* b_pred   = (const float*)d_in[7];
    const float* W_bin    = (const float*)d_in[8];
    const float* b_bin    = (const float*)d_in[9];
    const float* W_final  = (const float*)d_in[10];
    const float* b_final  = (const float*)d_in[11];
    unsigned short* ws = (unsigned short*)d_ws;
    float* out = (float*)d_out;

    hipLaunchKernelGGL(prep_kernel, dim3(128), dim3(256), 0, stream,
                       emb_pred, emb_var, emb_op, W_pred, W_bin, ws);
    hipLaunchKernelGGL(formula_kernel, dim3(4096 / NB), dim3(NTH), 0, stream,
                       pred_ids, arg_ids, op_ids, b_pred, b_bin, W_final, b_final,
                       (const unsigned short*)ws, out);
}

// Round 3
// 44.197 us; speedup vs baseline: 17.3735x; 2.7545x over previous
//
#include <hip/hip_runtime.h>

using short8 = __attribute__((ext_vector_type(8))) short;
using f32x4  = __attribute__((ext_vector_type(4))) float;

#define NB   16      // batch elements per block
#define NTH  512     // 8 waves
// d_ws layout (ushort units)
#define WPRED_OFF 0        // [64 n][384 k]
#define WBIN_OFF  24576    // [64 n][192 k]
#define WFIN_OFF  36864    // [160 n][64 k]
#define EMB_OFF   47104    // [300 r][64 k] linear (swizzled on LDS load)
#define WS_USHORTS 66304
// emb table base rows (within s_emb)
#define EMBP_R 0
#define EMBV_R 100
#define EMBO_R 200

__device__ __forceinline__ unsigned short f2b(float v) {
    unsigned x = __float_as_uint(v);
    unsigned r = (x + 0x7fffu + ((x >> 16) & 1u)) >> 16;
    return (unsigned short)r;
}
__device__ __forceinline__ short8 ld8s(const unsigned short* p) {
    return *reinterpret_cast<const short8*>(p);
}
__device__ __forceinline__ f32x4 mf(short8 a, short8 b, f32x4 c) {
    return __builtin_amdgcn_mfma_f32_16x16x32_bf16(a, b, c, 0, 0, 0);
}

// ---------------- prep: convert weights + embeddings to padded bf16 in ws ----
__global__ void prep_kernel(const float* __restrict__ emb_pred,
                            const float* __restrict__ emb_var,
                            const float* __restrict__ emb_op,
                            const float* __restrict__ W_pred,
                            const float* __restrict__ W_bin,
                            const float* __restrict__ W_final,
                            unsigned short* __restrict__ ws) {
    for (int i = blockIdx.x * blockDim.x + threadIdx.x; i < WS_USHORTS;
         i += gridDim.x * blockDim.x) {
        float v = 0.f;
        if (i < WBIN_OFF) {                     // W_pred_b [64][384]
            int n = i / 384, k = i - n * 384, p = k >> 6, j = k & 63;
            if (n < 50 && j < 50) v = W_pred[n * 300 + p * 50 + j];
        } else if (i < WFIN_OFF) {              // W_bin_b [64][192]
            int t = i - WBIN_OFF;
            int n = t / 192, k = t - n * 192, p = k >> 6, j = k & 63;
            if (n < 50 && j < 50) v = W_bin[n * 150 + p * 50 + j];
        } else if (i < EMB_OFF) {               // W_final_b [160][64]
            int t = i - WFIN_OFF;
            int o = t >> 6, k = t & 63;
            if (o < 155 && k < 50) v = W_final[o * 50 + k];
        } else {                                // emb linear [300][64]
            int t = i - EMB_OFF;
            int r = t >> 6, j = t & 63;
            if (j < 50) {
                if (r < 100)      v = emb_pred[r * 50 + j];
                else if (r < 200) v = emb_var[(r - 100) * 50 + j];
                else              v = emb_op[(r - 200) * 50 + j];
            }
        }
        ws[i] = f2b(v);
    }
}

// ---------------- main fused kernel -----------------------------------------
// Block = 16 batch. 8 waves = 2 subtree-groups x 4 N-tile waves.
// s_x rows (each [16 m][64 k] bf16, slot-swizzled by m&7):
//   group g base G=g*24: leaves G+0..15 | lev0 G+16..23 | lev1 G+0..3 | lev2 G+4..5
//   shared: lev3 48+st | lev4 52+g | root 54
// s_emb rows [300][64], slot-swizzled by r&7.
__global__ __launch_bounds__(NTH, 2) void formula_kernel(
    const int* __restrict__ pred_ids, const int* __restrict__ arg_ids,
    const int* __restrict__ op_ids,
    const float* __restrict__ b_pred, const float* __restrict__ b_bin,
    const float* __restrict__ b_final,
    const unsigned short* __restrict__ ws,
    float* __restrict__ out)
{
    __shared__ __align__(16) unsigned short s_x[55][1024];
    __shared__ __align__(16) unsigned short s_emb[300 * 64];
    __shared__ unsigned char s_pred[64 * 16];
    __shared__ unsigned char s_arg[320 * 16];
    __shared__ unsigned char s_op[63 * 16 + 16];

    const int tid  = threadIdx.x;
    const int b0   = blockIdx.x * NB;
    const int lane = tid & 63;
    const int w    = tid >> 6;       // wave 0..7
    const int g    = w >> 2;         // subtree group 0..1
    const int nt   = w & 3;          // N-tile 0..3
    const int l15  = lane & 15;
    const int quad = lane >> 4;
    const int n    = nt * 16 + l15;  // output neuron this lane owns
    const int G    = g * 24;

    // ---- stage embeddings into LDS (16B slots, swizzled by r&7) ----
    for (int i = tid; i < 300 * 8; i += NTH) {
        int r = i >> 3, s = i & 7;
        short8 v = ld8s(ws + EMB_OFF + r * 64 + s * 8);
        *reinterpret_cast<short8*>(&s_emb[r * 64 + ((s ^ (r & 7)) << 3)]) = v;
    }
    // ---- stage indices as u8, transposed to [entry][batch] ----
    for (int e = tid; e < 64 * 16; e += NTH) {
        int batch = e >> 6, lf = e & 63;
        s_pred[lf * 16 + batch] = (unsigned char)pred_ids[(b0 + batch) * 64 + lf];
    }
    for (int e = tid; e < 320 * 16; e += NTH) {
        int batch = e / 320, r = e - batch * 320;
        s_arg[r * 16 + batch] = (unsigned char)arg_ids[(b0 + batch) * 320 + r];
    }
    for (int e = tid; e < 63 * 16; e += NTH) {
        int batch = e / 63, r = e - batch * 63;
        s_op[r * 16 + batch] = (unsigned char)op_ids[(b0 + batch) * 63 + r];
    }

    // ---- persistent B fragments (weights) in registers ----
    short8 wp[6][2], wb[3][2];
    {
        const unsigned short* base = ws + WPRED_OFF + n * 384 + quad * 8;
        #pragma unroll
        for (int p = 0; p < 6; ++p) {
            wp[p][0] = ld8s(base + p * 64);
            wp[p][1] = ld8s(base + p * 64 + 32);
        }
        const unsigned short* bb = ws + WBIN_OFF + n * 192 + quad * 8;
        #pragma unroll
        for (int p = 0; p < 3; ++p) {
            wb[p][0] = ld8s(bb + p * 64);
            wb[p][1] = ld8s(bb + p * 64 + 32);
        }
    }
    const float bias_p = (n < 50) ? b_pred[n] : 0.f;
    const float bias_b = (n < 50) ? b_bin[n]  : 0.f;

    // A-fragment from a swizzled emb row r (half=0: k 0..31, half=1: k 32..63)
    auto embfrag = [&](int r, int half) {
        return ld8s(s_emb + r * 64 + (((quad + half * 4) ^ (r & 7)) << 3));
    };
    // A-fragment from an s_x activation row (batch m = l15, swizzle by m&7)
    auto tA = [&](const unsigned short* row, int half) {
        return ld8s(row + l15 * 64 + (((quad + half * 4) ^ (l15 & 7)) << 3));
    };
    // D: col=l15 (=n), row=quad*4+q (=batch m). ReLU+bias, swizzled bf16 store.
    auto epi = [&](f32x4 acc, float bias, unsigned short* row) {
        #pragma unroll
        for (int q = 0; q < 4; ++q) {
            int m = quad * 4 + q;
            float v = fmaxf(acc[q] + bias, 0.f);
            row[m * 64 + (((n >> 3) ^ (m & 7)) << 3) + (n & 7)] = f2b(v);
        }
    };

    // two leaves with independent acc chains
    auto leafpair = [&](int gl, int dst) {
        f32x4 a0 = {0.f,0.f,0.f,0.f}, a1 = {0.f,0.f,0.f,0.f};
        int ip0 = s_pred[gl * 16 + l15], ip1 = s_pred[(gl + 1) * 16 + l15];
        int ia0[5], ia1[5];
        #pragma unroll
        for (int a = 0; a < 5; ++a) {
            ia0[a] = s_arg[(gl * 5 + a) * 16 + l15];
            ia1[a] = s_arg[((gl + 1) * 5 + a) * 16 + l15];
        }
        int r0 = EMBP_R + ip0, r1 = EMBP_R + ip1;
        a0 = mf(embfrag(r0, 0), wp[0][0], a0);
        a1 = mf(embfrag(r1, 0), wp[0][0], a1);
        a0 = mf(embfrag(r0, 1), wp[0][1], a0);
        a1 = mf(embfrag(r1, 1), wp[0][1], a1);
        #pragma unroll
        for (int a = 0; a < 5; ++a) {
            int v0 = EMBV_R + ia0[a], v1 = EMBV_R + ia1[a];
            a0 = mf(embfrag(v0, 0), wp[1 + a][0], a0);
            a1 = mf(embfrag(v1, 0), wp[1 + a][0], a1);
            a0 = mf(embfrag(v0, 1), wp[1 + a][1], a0);
            a1 = mf(embfrag(v1, 1), wp[1 + a][1], a1);
        }
        epi(a0, bias_p, s_x[dst]);
        epi(a1, bias_p, s_x[dst + 1]);
    };

    // one / two tree nodes
    auto tnode = [&](int cl, int cr, int gn, int dst) {
        f32x4 acc = {0.f,0.f,0.f,0.f};
        int r = EMBO_R + s_op[gn * 16 + l15];
        acc = mf(tA(s_x[cl], 0), wb[0][0], acc);
        acc = mf(tA(s_x[cl], 1), wb[0][1], acc);
        acc = mf(embfrag(r, 0), wb[1][0], acc);
        acc = mf(embfrag(r, 1), wb[1][1], acc);
        acc = mf(tA(s_x[cr], 0), wb[2][0], acc);
        acc = mf(tA(s_x[cr], 1), wb[2][1], acc);
        epi(acc, bias_b, s_x[dst]);
    };
    auto tnode2 = [&](int cl0, int cr0, int gn0, int d0,
                      int cl1, int cr1, int gn1, int d1) {
        f32x4 a0 = {0.f,0.f,0.f,0.f}, a1 = {0.f,0.f,0.f,0.f};
        int r0 = EMBO_R + s_op[gn0 * 16 + l15];
        int r1 = EMBO_R + s_op[gn1 * 16 + l15];
        a0 = mf(tA(s_x[cl0], 0), wb[0][0], a0);
        a1 = mf(tA(s_x[cl1], 0), wb[0][0], a1);
        a0 = mf(tA(s_x[cl0], 1), wb[0][1], a0);
        a1 = mf(tA(s_x[cl1], 1), wb[0][1], a1);
        a0 = mf(embfrag(r0, 0), wb[1][0], a0);
        a1 = mf(embfrag(r1, 0), wb[1][0], a1);
        a0 = mf(embfrag(r0, 1), wb[1][1], a0);
        a1 = mf(embfrag(r1, 1), wb[1][1], a1);
        a0 = mf(tA(s_x[cr0], 0), wb[2][0], a0);
        a1 = mf(tA(s_x[cr1], 0), wb[2][0], a1);
        a0 = mf(tA(s_x[cr0], 1), wb[2][1], a0);
        a1 = mf(tA(s_x[cr1], 1), wb[2][1], a1);
        epi(a0, bias_b, s_x[d0]);
        epi(a1, bias_b, s_x[d1]);
    };

    __syncthreads();

    #pragma unroll
    for (int sp = 0; sp < 2; ++sp) {
        const int st = 2 * g + sp;           // subtree 0..3
        // ---- leaves: 8 pairs ----
        #pragma unroll
        for (int p = 0; p < 8; ++p)
            leafpair(st * 16 + 2 * p, G + 2 * p);
        __syncthreads();
        // ---- lev0: 8 nodes (4 pairs) -> G+16..23 ----
        #pragma unroll
        for (int p = 0; p < 4; ++p)
            tnode2(G + 4*p,     G + 4*p + 1, st*8 + 2*p,     G + 16 + 2*p,
                   G + 4*p + 2, G + 4*p + 3, st*8 + 2*p + 1, G + 16 + 2*p + 1);
        __syncthreads();
        // ---- lev1: 4 nodes (2 pairs) -> G+0..3 ----
        #pragma unroll
        for (int p = 0; p < 2; ++p)
            tnode2(G + 16 + 4*p,     G + 16 + 4*p + 1, 32 + st*4 + 2*p,     G + 2*p,
                   G + 16 + 4*p + 2, G + 16 + 4*p + 3, 32 + st*4 + 2*p + 1, G + 2*p + 1);
        __syncthreads();
        // ---- lev2: 2 nodes -> G+4..5 ----
        tnode2(G + 0, G + 1, 48 + st*2,     G + 4,
               G + 2, G + 3, 48 + st*2 + 1, G + 5);
        __syncthreads();
        // ---- lev3: 1 node -> shared 48+st ----
        tnode(G + 4, G + 5, 56 + st, 48 + st);
        __syncthreads();
    }
    // ---- lev4: group g computes node g -> 52+g ----
    tnode(48 + 2*g, 48 + 2*g + 1, 60 + g, 52 + g);
    __syncthreads();
    // ---- lev5 (root) -> 54 ----
    if (g == 0) tnode(52, 53, 62, 54);
    __syncthreads();

    // ---- final head via MFMA: 10 N-tiles over 8 waves ----
    auto headtile = [&](int t) {
        f32x4 acc = {0.f,0.f,0.f,0.f};
        int n2 = t * 16 + l15;
        const unsigned short* bf = ws + WFIN_OFF + n2 * 64 + quad * 8;
        acc = mf(tA(s_x[54], 0), ld8s(bf),      acc);
        acc = mf(tA(s_x[54], 1), ld8s(bf + 32), acc);
        float bias = (n2 < 155) ? b_final[n2] : 0.f;
        #pragma unroll
        for (int q = 0; q < 4; ++q) {
            int m = quad * 4 + q;
            if (n2 < 155) out[(b0 + m) * 155 + n2] = acc[q] + bias;
        }
    };
    headtile(w);
    if (w < 2) headtile(8 + w);
}

extern "C" void kernel_launch(void* const* d_in, const int* in_sizes, int n_in,
                              void* d_out, int out_size, void* d_ws, size_t ws_size,
                              hipStream_t stream) {
    const int*   pred_ids = (const int*)  d_in[0];
    const int*   arg_ids  = (const int*)  d_in[1];
    const int*   op_ids   = (const int*)  d_in[2];
    const float* emb_pred = (const float*)d_in[3];
    const float* emb_var  = (const float*)d_in[4];
    const float* emb_op   = (const float*)d_in[5];
    const float* W_pred   = (const float*)d_in[6];
    const float* b_pred   = (const float*)d_in[7];
    const float* W_bin    = (const float*)d_in[8];
    const float* b_bin    = (const float*)d_in[9];
    const float* W_final  = (const float*)d_in[10];
    const float* b_final  = (const float*)d_in[11];
    unsigned short* ws = (unsigned short*)d_ws;
    float* out = (float*)d_out;

    hipLaunchKernelGGL(prep_kernel, dim3(128), dim3(256), 0, stream,
                       emb_pred, emb_var, emb_op, W_pred, W_bin, W_final, ws);
    hipLaunchKernelGGL(formula_kernel, dim3(4096 / NB), dim3(NTH), 0, stream,
                       pred_ids, arg_ids, op_ids, b_pred, b_bin, b_final,
                       (const unsigned short*)ws, out);
}

// Round 5
// 35.596 us; speedup vs baseline: 21.5715x; 1.2416x over previous
//
#include <hip/hip_runtime.h>

using short8 = __attribute__((ext_vector_type(8))) short;
using h8     = __attribute__((ext_vector_type(8))) _Float16;
using h2     = __attribute__((ext_vector_type(2))) _Float16;
using f32x4  = __attribute__((ext_vector_type(4))) float;

#define NB  16
#define NTH 512
// ws layout (ushort units, all f16 bits)
#define WBIN_OFF 0         // [64 n][192 k]
#define WFIN_OFF 12288     // [160 n][64 k]
#define EMBO_OFF 22528     // [100 r][64 k]
#define LTAB_OFF 28928     // [6 p][100 v][64 n]
#define WS_USHORTS 67328

__device__ __forceinline__ unsigned short f2h_bits(float v) {
    _Float16 h = (_Float16)v;
    return *reinterpret_cast<unsigned short*>(&h);
}
__device__ __forceinline__ h8 ld8h(const unsigned short* p) {
    return *reinterpret_cast<const h8*>(p);
}
__device__ __forceinline__ short8 ld8s(const unsigned short* p) {
    return *reinterpret_cast<const short8*>(p);
}
__device__ __forceinline__ f32x4 mf(h8 a, h8 b, f32x4 c) {
    return __builtin_amdgcn_mfma_f32_16x16x32_f16(a, b, c, 0, 0, 0);
}

// ---------------- prep: build f16 weights + leaf lookup tables --------------
__global__ void prep_kernel(const float* __restrict__ emb_pred,
                            const float* __restrict__ emb_var,
                            const float* __restrict__ emb_op,
                            const float* __restrict__ W_pred,
                            const float* __restrict__ W_bin,
                            const float* __restrict__ W_final,
                            unsigned short* __restrict__ ws) {
    for (int i = blockIdx.x * blockDim.x + threadIdx.x; i < WS_USHORTS;
         i += gridDim.x * blockDim.x) {
        float v = 0.f;
        if (i < WFIN_OFF) {                      // W_bin [64][192]
            int n = i / 192, k = i - n * 192, p = k >> 6, j = k & 63;
            if (n < 50 && j < 50) v = W_bin[n * 150 + p * 50 + j];
        } else if (i < EMBO_OFF) {               // W_final [160][64]
            int t = i - WFIN_OFF, o = t >> 6, k = t & 63;
            if (o < 155 && k < 50) v = W_final[o * 50 + k];
        } else if (i < LTAB_OFF) {               // emb_op [100][64]
            int t = i - EMBO_OFF, r = t >> 6, j = t & 63;
            if (j < 50) v = emb_op[r * 50 + j];
        } else {                                 // leaf tables [6][100][64]
            int t = i - LTAB_OFF;
            int p = t / 6400, rest = t - p * 6400, vv = rest >> 6, n = rest & 63;
            if (n < 50) {
                const float* e = (p == 0) ? (emb_pred + vv * 50) : (emb_var + vv * 50);
                const float* wr = W_pred + n * 300 + p * 50;
                float acc = 0.f;
                for (int k = 0; k < 50; ++k) acc += e[k] * wr[k];
                v = acc;
            }
        }
        ws[i] = f2h_bits(v);
    }
}

// one tree node, compile-time N-tile subset [NT0, NT0+NTN)
#define TNODE(NT0, NTN, CL, CR, GN, DST) do {                                   \
    const unsigned short* rl_ = s_x[CL];                                        \
    const unsigned short* rr_ = s_x[CR];                                        \
    int r_ = s_op[(GN) * 16 + l15];                                             \
    h8 aL0 = ld8h(rl_ + l15 * 64 + ((quad ^ (l15 & 7)) << 3));                  \
    h8 aL1 = ld8h(rl_ + l15 * 64 + (((quad + 4) ^ (l15 & 7)) << 3));            \
    h8 aO0 = ld8h(s_embop + r_ * 64 + ((quad ^ (r_ & 7)) << 3));                \
    h8 aO1 = ld8h(s_embop + r_ * 64 + (((quad + 4) ^ (r_ & 7)) << 3));          \
    h8 aR0 = ld8h(rr_ + l15 * 64 + ((quad ^ (l15 & 7)) << 3));                  \
    h8 aR1 = ld8h(rr_ + l15 * 64 + (((quad + 4) ^ (l15 & 7)) << 3));            \
    f32x4 acc_[NTN];                                                            \
    _Pragma("unroll") for (int i_ = 0; i_ < (NTN); ++i_) {                      \
        acc_[i_] = (f32x4){0.f, 0.f, 0.f, 0.f};                                 \
        acc_[i_] = mf(aL0, wb[0][0][(NT0) + i_], acc_[i_]);                     \
        acc_[i_] = mf(aL1, wb[0][1][(NT0) + i_], acc_[i_]);                     \
        acc_[i_] = mf(aO0, wb[1][0][(NT0) + i_], acc_[i_]);                     \
        acc_[i_] = mf(aO1, wb[1][1][(NT0) + i_], acc_[i_]);                     \
        acc_[i_] = mf(aR0, wb[2][0][(NT0) + i_], acc_[i_]);                     \
        acc_[i_] = mf(aR1, wb[2][1][(NT0) + i_], acc_[i_]);                     \
    }                                                                           \
    unsigned short* drow_ = s_x[DST];                                           \
    _Pragma("unroll") for (int i_ = 0; i_ < (NTN); ++i_) {                      \
        int n_ = ((NT0) + i_) * 16 + l15;                                       \
        _Pragma("unroll") for (int q_ = 0; q_ < 4; ++q_) {                      \
            int m_ = quad * 4 + q_;                                             \
            float v_ = fmaxf(acc_[i_][q_] + biasb[(NT0) + i_], 0.f);            \
            drow_[m_ * 64 + (((n_ >> 3) ^ (m_ & 7)) << 3) + (n_ & 7)] = f2h_bits(v_); \
        }                                                                       \
    }                                                                           \
} while (0)

// ---------------- main fused kernel -----------------------------------------
__global__ __launch_bounds__(NTH, 2) void formula_kernel(
    const int* __restrict__ pred_ids, const int* __restrict__ arg_ids,
    const int* __restrict__ op_ids,
    const float* __restrict__ b_pred, const float* __restrict__ b_bin,
    const float* __restrict__ b_final,
    const unsigned short* __restrict__ ws,
    float* __restrict__ out)
{
    __shared__ __align__(16) unsigned short s_ltab[6 * 100 * 64];  // 76800 B
    __shared__ __align__(16) unsigned short s_embop[100 * 64];     // 12800 B
    __shared__ __align__(16) unsigned short s_x[31][1024];         // 63488 B
    __shared__ __align__(8)  unsigned char  s_ids[64][16][8];      //  8192 B
    __shared__ unsigned char s_op[64 * 16];                        //  1024 B

    const int tid  = threadIdx.x;
    const int b0   = blockIdx.x * NB;
    const int lane = tid & 63;
    const int w    = tid >> 6;
    const int l15  = lane & 15;
    const int quad = lane >> 4;
    const int cg   = tid & 7;     // constant col-group per thread (leaf phase)

    // ---- stage leaf tables (linear) + op emb (swizzled) ----
    for (int i = tid; i < 6 * 100 * 8; i += NTH)
        *reinterpret_cast<short8*>(&s_ltab[i * 8]) = ld8s(ws + LTAB_OFF + i * 8);
    for (int i = tid; i < 100 * 8; i += NTH) {
        int r = i >> 3, s = i & 7;
        *reinterpret_cast<short8*>(&s_embop[r * 64 + ((s ^ (r & 7)) << 3)]) =
            ld8s(ws + EMBO_OFF + r * 64 + s * 8);
    }
    // ---- stage ids: s_ids[leaf][m] = {pred, a0..a4, 0, 0} ----
    for (int e = tid; e < 64 * 16; e += NTH) {
        int lf = e >> 4, m = e & 15;
        unsigned char* rec = &s_ids[lf][m][0];
        rec[0] = (unsigned char)pred_ids[(b0 + m) * 64 + lf];
        #pragma unroll
        for (int a = 0; a < 5; ++a)
            rec[1 + a] = (unsigned char)arg_ids[(b0 + m) * 320 + lf * 5 + a];
        rec[6] = 0; rec[7] = 0;
    }
    for (int e = tid; e < 63 * 16; e += NTH) {
        int r = e >> 4, m = e & 15;
        s_op[r * 16 + m] = (unsigned char)op_ids[(b0 + m) * 63 + r];
    }

    // ---- persistent W_bin fragments: all 4 N-tiles in regs (96 VGPR) ----
    short8 wb_raw[3][2][4];
    #pragma unroll
    for (int p = 0; p < 3; ++p)
        #pragma unroll
        for (int h = 0; h < 2; ++h)
            #pragma unroll
            for (int nt = 0; nt < 4; ++nt)
                wb_raw[p][h][nt] = ld8s(ws + WBIN_OFF + (nt * 16 + l15) * 192
                                        + p * 64 + (quad + 4 * h) * 8);
    h8 (&wb)[3][2][4] = reinterpret_cast<h8(&)[3][2][4]>(wb_raw);

    float biasb[4];
    #pragma unroll
    for (int nt = 0; nt < 4; ++nt) {
        int n = nt * 16 + l15;
        biasb[nt] = (n < 50) ? b_bin[n] : 0.f;
    }
    h2 bias2[4];
    #pragma unroll
    for (int k = 0; k < 4; ++k) {
        int n0 = cg * 8 + 2 * k, n1 = n0 + 1;
        bias2[k] = (h2){(_Float16)((n0 < 50) ? b_pred[n0] : 0.f),
                        (_Float16)((n1 < 50) ? b_pred[n1] : 0.f)};
    }
    const h2 z2 = (h2){(_Float16)0.f, (_Float16)0.f};

    __syncthreads();

    for (int st = 0; st < 4; ++st) {
        // ---- leaf layer: 16 leaves x 16 m x 8 colgroups = 2048 jobs ----
        #pragma unroll
        for (int p4 = 0; p4 < 4; ++p4) {
            int job = p4 * NTH + tid;
            int lfl = job >> 7;            // 0..15
            int m   = (job >> 3) & 15;
            int lf  = st * 16 + lfl;
            const unsigned int* ivp =
                reinterpret_cast<const unsigned int*>(&s_ids[lf][m][0]);
            unsigned int ix = ivp[0], iy = ivp[1];
            int r0 = ix & 255, r1 = (ix >> 8) & 255, r2 = (ix >> 16) & 255;
            int r3 = ix >> 24, r4 = iy & 255, r5 = (iy >> 8) & 255;
            h2 a0 = bias2[0], a1 = bias2[1], a2 = bias2[2], a3 = bias2[3];
            #define ACCT(ROW, P) {                                              \
                h8 t_ = ld8h(s_ltab + (P) * 6400 + (ROW) * 64 + cg * 8);        \
                const h2* tp_ = reinterpret_cast<const h2*>(&t_);               \
                a0 += tp_[0]; a1 += tp_[1]; a2 += tp_[2]; a3 += tp_[3]; }
            ACCT(r0, 0); ACCT(r1, 1); ACCT(r2, 2);
            ACCT(r3, 3); ACCT(r4, 4); ACCT(r5, 5);
            #undef ACCT
            a0 = __builtin_elementwise_max(a0, z2);
            a1 = __builtin_elementwise_max(a1, z2);
            a2 = __builtin_elementwise_max(a2, z2);
            a3 = __builtin_elementwise_max(a3, z2);
            union { h2 h[4]; short8 s; } u;
            u.h[0] = a0; u.h[1] = a1; u.h[2] = a2; u.h[3] = a3;
            *reinterpret_cast<short8*>(
                &s_x[lfl][m * 64 + ((cg ^ (m & 7)) << 3)]) = u.s;
        }
        __syncthreads();
        // ---- lev0: 8 nodes, wave w = node w ----
        TNODE(0, 4, 2 * w, 2 * w + 1, st * 8 + w, 16 + w);
        __syncthreads();
        // ---- lev1: 4 nodes x 2 ntile-pairs ----
        {
            int j = w >> 1;
            int cl = 16 + 2 * j, cr = 17 + 2 * j, gn = 32 + st * 4 + j, dst = j;
            if ((w & 1) == 0) TNODE(0, 2, cl, cr, gn, dst);
            else              TNODE(2, 2, cl, cr, gn, dst);
        }
        __syncthreads();
        // ---- lev2: 2 nodes x 4 ntiles ----
        {
            int j = w >> 2;
            int cl = 2 * j, cr = 2 * j + 1, gn = 48 + st * 2 + j, dst = 16 + j;
            switch (w & 3) {
                case 0: TNODE(0, 1, cl, cr, gn, dst); break;
                case 1: TNODE(1, 1, cl, cr, gn, dst); break;
                case 2: TNODE(2, 1, cl, cr, gn, dst); break;
                default: TNODE(3, 1, cl, cr, gn, dst); break;
            }
        }
        __syncthreads();
        // ---- lev3: 1 node x 4 ntiles (waves 0..3) ----
        if (w < 4) {
            int gn = 56 + st, dst = 24 + st;
            switch (w) {
                case 0: TNODE(0, 1, 16, 17, gn, dst); break;
                case 1: TNODE(1, 1, 16, 17, gn, dst); break;
                case 2: TNODE(2, 1, 16, 17, gn, dst); break;
                default: TNODE(3, 1, 16, 17, gn, dst); break;
            }
        }
        __syncthreads();
    }
    // ---- lev4: 2 nodes x 4 ntiles ----
    {
        int gg = w >> 2;
        int cl = 24 + 2 * gg, cr = 25 + 2 * gg, gn = 60 + gg, dst = 28 + gg;
        switch (w & 3) {
            case 0: TNODE(0, 1, cl, cr, gn, dst); break;
            case 1: TNODE(1, 1, cl, cr, gn, dst); break;
            case 2: TNODE(2, 1, cl, cr, gn, dst); break;
            default: TNODE(3, 1, cl, cr, gn, dst); break;
        }
    }
    __syncthreads();
    // ---- lev5 (root, waves 0..3) ----
    if (w < 4) {
        switch (w) {
            case 0: TNODE(0, 1, 28, 29, 62, 30); break;
            case 1: TNODE(1, 1, 28, 29, 62, 30); break;
            case 2: TNODE(2, 1, 28, 29, 62, 30); break;
            default: TNODE(3, 1, 28, 29, 62, 30); break;
        }
    }
    __syncthreads();

    // ---- final head via MFMA: 10 N-tiles ----
    auto headtile = [&](int t) {
        f32x4 acc = {0.f, 0.f, 0.f, 0.f};
        int n2 = t * 16 + l15;
        const unsigned short* rroot = s_x[30];
        h8 x0 = ld8h(rroot + l15 * 64 + ((quad ^ (l15 & 7)) << 3));
        h8 x1 = ld8h(rroot + l15 * 64 + (((quad + 4) ^ (l15 & 7)) << 3));
        acc = mf(x0, ld8h(ws + WFIN_OFF + n2 * 64 + quad * 8), acc);
        acc = mf(x1, ld8h(ws + WFIN_OFF + n2 * 64 + (quad + 4) * 8), acc);
        if (n2 < 155) {
            float bias = b_final[n2];
            #pragma unroll
            for (int q = 0; q < 4; ++q) {
                int m = quad * 4 + q;
                out[(b0 + m) * 155 + n2] = acc[q] + bias;
            }
        }
    };
    headtile(w);
    if (w < 2) headtile(8 + w);
}

extern "C" void kernel_launch(void* const* d_in, const int* in_sizes, int n_in,
                              void* d_out, int out_size, void* d_ws, size_t ws_size,
                              hipStream_t stream) {
    const int*   pred_ids = (const int*)  d_in[0];
    const int*   arg_ids  = (const int*)  d_in[1];
    const int*   op_ids   = (const int*)  d_in[2];
    const float* emb_pred = (const float*)d_in[3];
    const float* emb_var  = (const float*)d_in[4];
    const float* emb_op   = (const float*)d_in[5];
    const float* W_pred   = (const float*)d_in[6];
    const float* b_pred   = (const float*)d_in[7];
    const float* W_bin    = (const float*)d_in[8];
    const float* b_bin    = (const float*)d_in[9];
    const float* W_final  = (const float*)d_in[10];
    const float* b_final  = (const float*)d_in[11];
    unsigned short* ws = (unsigned short*)d_ws;
    float* out = (float*)d_out;

    hipLaunchKernelGGL(prep_kernel, dim3(256), dim3(256), 0, stream,
                       emb_pred, emb_var, emb_op, W_pred, W_bin, W_final, ws);
    hipLaunchKernelGGL(formula_kernel, dim3(4096 / NB), dim3(NTH), 0, stream,
                       pred_ids, arg_ids, op_ids, b_pred, b_bin, b_final,
                       (const unsigned short*)ws, out);
}